// Round 6
// baseline (429.220 us; speedup 1.0000x reference)
//
#include <hip/hip_runtime.h>

#define KDIM 1024
#define NDIM 4096

typedef __attribute__((ext_vector_type(4))) float f32x4;
typedef __attribute__((ext_vector_type(8))) short s16x8;
typedef __attribute__((ext_vector_type(8))) unsigned short u16x8;

__device__ __forceinline__ unsigned short f2bf(float f) {
    union { float f; unsigned u; } v; v.f = f;
    unsigned r = v.u + 0x7FFFu + ((v.u >> 16) & 1u);
    return (unsigned short)(r >> 16);
}

#define GLDS(gsrc, ldst)                                                        \
    __builtin_amdgcn_global_load_lds(                                           \
        (const __attribute__((address_space(1))) unsigned int*)(gsrc),          \
        (__attribute__((address_space(3))) unsigned int*)(ldst), 16, 0, 0)

#define SBAR() __builtin_amdgcn_s_barrier()
#define VMW(n) asm volatile("s_waitcnt vmcnt(" #n ")" ::: "memory")
#define LGKM0() asm volatile("s_waitcnt lgkmcnt(0)" ::: "memory")

__device__ __forceinline__ void row_coeffs(int o, const float* w,
                                           float& rp0, float& rp1, float& rp2) {
    rp2 = (o < 2048 ? w[6] : 0.f) + (o < 3072 ? w[7] : 0.f) + w[8];
    rp1 = rp2 + (o < 1536 ? w[3] : 0.f) + (o < 2304 ? w[4] : 0.f) + (o < 3072 ? w[5] : 0.f);
    rp0 = rp1 + (o < 1024 ? w[0] : 0.f) + (o < 1536 ? w[1] : 0.f) + (o < 2048 ? w[2] : 0.f);
}

__device__ __forceinline__ float row_bias_coef(int n, const float* w) {
    return (n < 1024 ? w[0] : 0.f) + (n < 1536 ? w[1] : 0.f)
         + (n < 2048 ? w[2] : 0.f) + (n < 1536 ? w[3] : 0.f)
         + (n < 2304 ? w[4] : 0.f) + (n < 3072 ? w[5] : 0.f)
         + (n < 2048 ? w[6] : 0.f) + (n < 3072 ? w[7] : 0.f) + w[8];
}

// ---------------- pre-pass: X f32 -> bf16 ----------------
__global__ __launch_bounds__(256) void prep_x(const float* __restrict__ X,
                                              unsigned short* __restrict__ XB, int n8) {
    int i = blockIdx.x * blockDim.x + threadIdx.x;
    const int stride = gridDim.x * blockDim.x;
    for (; i < n8; i += stride) {
        const f32x4* p = (const f32x4*)(X + (size_t)i * 8);
        f32x4 a = p[0], b = p[1];
        u16x8 o;
        o[0] = f2bf(a[0]); o[1] = f2bf(a[1]); o[2] = f2bf(a[2]); o[3] = f2bf(a[3]);
        o[4] = f2bf(b[0]); o[5] = f2bf(b[1]); o[6] = f2bf(b[2]); o[7] = f2bf(b[3]);
        *(u16x8*)(XB + (size_t)i * 8) = o;
    }
}

// ---------------- pre-pass: W_mix = W * coeff -> bf16 ----------------
__global__ __launch_bounds__(256) void prep_w(const float* __restrict__ W,
                                              const float* __restrict__ wts,
                                              unsigned short* __restrict__ WB) {
    const int g = blockIdx.x * blockDim.x + threadIdx.x;
    if (g >= NDIM * (KDIM / 8)) return;
    const int o = g >> 7, ig = g & 127;
    float w[9];
#pragma unroll
    for (int k = 0; k < 9; ++k) w[k] = wts[k];
    float rp0, rp1, rp2;
    row_coeffs(o, w, rp0, rp1, rp2);
    const float cf = ig < 64 ? rp0 : (ig < 96 ? rp1 : rp2);
    const f32x4* p = (const f32x4*)(W + (size_t)g * 8);
    f32x4 a = p[0], b = p[1];
    u16x8 ov;
    ov[0] = f2bf(a[0] * cf); ov[1] = f2bf(a[1] * cf); ov[2] = f2bf(a[2] * cf); ov[3] = f2bf(a[3] * cf);
    ov[4] = f2bf(b[0] * cf); ov[5] = f2bf(b[1] * cf); ov[6] = f2bf(b[2] * cf); ov[7] = f2bf(b[3] * cf);
    *(u16x8*)(WB + (size_t)g * 8) = ov;
}

// ---------------- main GEMM v6: 128x128, 4 waves, reg-double-buffered frags ----------------
// Key idea: fragments for K-tile kt+1 are ds_read DURING kt's MFMA cluster (no
// dependency -> LDS pipe and MFMA pipe overlap within each wave). Ring-3 LDS
// (48 KiB) keeps 3 K-tiles: o1 = being read, o2 = landing, o0 = being staged
// (kt+3, its loads ride across the barrier -> vmcnt(4), never drained mid-loop).
// ~150 VGPR -> 2-3 blocks/CU co-resident: unsynchronized blocks fill each
// other's sync bubbles (m114). L2 mapping: each XCD owns 4 n_tiles (WB panel
// 1 MB L2-resident); 4 consecutive blocks share one m_tile (XB tile L2-hot).
__global__ __launch_bounds__(256, 2) void mlv2_gemm_v6(
    const unsigned short* __restrict__ XB,
    const unsigned short* __restrict__ WB,
    const float* __restrict__ wts,
    const float* __restrict__ bias,
    float* __restrict__ Y,
    int nm)   // number of m_tiles = M/128
{
    __shared__ unsigned short LDS[3 * 8192];   // 48 KiB: 3 bufs x (A 4096 + B 4096) ushorts

    const int tid = (int)threadIdx.x;
    const int l   = tid & 63;
    const int w   = tid >> 6;      // wave 0..3
    const int wm  = w >> 1;        // 0..1
    const int wn  = w & 1;         // 0..1

    const int bid = (int)blockIdx.x;
    const int xcd = bid & 7;
    const int idx = bid >> 3;
    const int n_tile = xcd * 4 + (idx & 3);    // XCD owns 4 n-tiles (WB panel L2-resident)
    const int m_tile = idx >> 2;               // 4 consecutive blocks share m_tile
    const int m0 = m_tile * 128;
    const int n0 = n_tile * 128;

    // ---- frag-read lane constants (chunk swizzle collapses to lane constant)
    const int rl = l & 15;
    const unsigned cw = (unsigned)(((l >> 4) ^ ((l >> 1) & 3)) * 8);
    unsigned offA[4], offB[4];
#pragma unroll
    for (int m = 0; m < 4; ++m)
        offA[m] = (unsigned)((wm * 64 + m * 16 + rl) * 32) + cw;
#pragma unroll
    for (int n = 0; n < 4; ++n)
        offB[n] = 4096u + (unsigned)((wn * 64 + n * 16 + rl) * 32) + cw;

    // ---- staging: wave w stages rows [32w,32w+32) of A and B; linear LDS dest,
    // inverse-swizzled per-lane global source (chunk c of row r at c ^ ((r>>1)&3)).
    const int cg = (((l & 3) ^ ((l >> 3) & 3)) * 8);
    const int r0 = w * 32 + (l >> 2);
    const unsigned short* sA0 = XB + (size_t)(m0 + r0) * KDIM + cg;
    const unsigned short* sA1 = XB + (size_t)(m0 + r0 + 16) * KDIM + cg;
    const unsigned short* sB0 = WB + (size_t)(n0 + r0) * KDIM + cg;
    const unsigned short* sB1 = WB + (size_t)(n0 + r0 + 16) * KDIM + cg;
    const unsigned dA0 = (unsigned)(w * 1024);
    const unsigned dA1 = dA0 + 512;
    const unsigned dB0 = 4096u + dA0;
    const unsigned dB1 = 4096u + dA1;

    auto stage = [&](unsigned ob, int kt) {
        const int ko = kt * 32;
        GLDS(sA0 + ko, &LDS[ob + dA0]);
        GLDS(sA1 + ko, &LDS[ob + dA1]);
        GLDS(sB0 + ko, &LDS[ob + dB0]);
        GLDS(sB1 + ko, &LDS[ob + dB1]);
    };

    f32x4 acc[4][4];
#pragma unroll
    for (int m = 0; m < 4; ++m)
#pragma unroll
        for (int n = 0; n < 4; ++n) acc[m][n] = (f32x4){0.f, 0.f, 0.f, 0.f};

    s16x8 a0[4], b0[4], a1[4], b1[4];   // two named frag sets (static indexing)

    auto rd = [&](s16x8 a[4], s16x8 b[4], unsigned ob) {
#pragma unroll
        for (int n = 0; n < 4; ++n) b[n] = *(const s16x8*)&LDS[ob + offB[n]];
#pragma unroll
        for (int m = 0; m < 4; ++m) a[m] = *(const s16x8*)&LDS[ob + offA[m]];
    };
    auto mm = [&](const s16x8 a[4], const s16x8 b[4]) {
        __builtin_amdgcn_s_setprio(1);
#pragma unroll
        for (int m = 0; m < 4; ++m)
#pragma unroll
            for (int n = 0; n < 4; ++n)
                acc[m][n] = __builtin_amdgcn_mfma_f32_16x16x32_bf16(
                    a[m], b[n], acc[m][n], 0, 0, 0);
        __builtin_amdgcn_s_setprio(0);
    };

    unsigned o0 = 0, o1 = 8192, o2 = 16384;   // ushort offsets; invariant at iter kt:
                                              // o0=buf[kt%3] (stage kt+3), o1=buf[(kt+1)%3] (read), o2=landing

    // prologue: stage kt 0,1,2; wait kt0; preload frags(0); wait kt1
    stage(o0, 0); stage(o1, 1); stage(o2, 2);
    VMW(8);
    SBAR();
    rd(a0, b0, o0);           // frags for kt=0
    VMW(4);                   // kt1 landed; kt2 in flight
    LGKM0();                  // preload reads drained (o0 overwritten next)
    SBAR();

#define ROT() { unsigned t_ = o0; o0 = o1; o1 = o2; o2 = t_; }

    // steady: 2x-unrolled (reg ping-pong), per iter kt:
    //   stage(kt+3)->o0 | read frags(kt+1)<-o1 | MFMA frags(kt) | vmcnt(4) lgkm0 bar
    for (int kt = 0; kt < 28; kt += 2) {
        stage(o0, kt + 3);
        rd(a1, b1, o1);
        mm(a0, b0);
        VMW(4); LGKM0(); SBAR();
        ROT();

        stage(o0, kt + 4);
        rd(a0, b0, o1);
        mm(a1, b1);
        VMW(4); LGKM0(); SBAR();
        ROT();
    }
    // kt=28: stage 31; read 29; mfma 28
    stage(o0, 31);
    rd(a1, b1, o1);
    mm(a0, b0);
    VMW(4); LGKM0(); SBAR();
    ROT();
    // kt=29: read 30; mfma 29; drain 31's loads
    rd(a0, b0, o1);
    mm(a1, b1);
    VMW(0); LGKM0(); SBAR();
    ROT();
    // kt=30: read 31; mfma 30
    rd(a1, b1, o1);
    mm(a0, b0);
    LGKM0();
    // kt=31
    mm(a1, b1);

    // ---- epilogue: + bias[n] * rowcoef(n)
    float w9[9];
#pragma unroll
    for (int k = 0; k < 9; ++k) w9[k] = wts[k];
    const int gmb = m0 + wm * 64 + (l >> 4) * 4;
    const int gnb = n0 + wn * 64 + rl;
#pragma unroll
    for (int n = 0; n < 4; ++n) {
        const int gn = gnb + n * 16;
        const float bc = bias[gn] * row_bias_coef(gn, w9);
#pragma unroll
        for (int m = 0; m < 4; ++m) {
            float* yp = Y + (size_t)(gmb + m * 16) * NDIM + gn;
            yp[0 * NDIM] = acc[m][n][0] + bc;
            yp[1 * NDIM] = acc[m][n][1] + bc;
            yp[2 * NDIM] = acc[m][n][2] + bc;
            yp[3 * NDIM] = acc[m][n][3] + bc;
        }
    }
#undef ROT
}

// ---------------- fallback (round-1 fused kernel, validated) ----------------
__global__ __launch_bounds__(256, 2) void mlv2_gemm_v1(
    const float* __restrict__ X, const float* __restrict__ wts,
    const float* __restrict__ W, const float* __restrict__ bias,
    float* __restrict__ Y)
{
    __shared__ unsigned short Alds[2][4][128][8];
    __shared__ unsigned short Blds[2][4][128][8];
    const int tid = (int)threadIdx.x;
    const int bid = (int)blockIdx.x;
    const int wg  = (bid & 7) * 1024 + (bid >> 3);
    const int n_tile = wg & 31;
    const int m_tile = wg >> 5;
    float w[9];
#pragma unroll
    for (int k = 0; k < 9; ++k) w[k] = wts[k];
    const int srow = tid >> 1;
    const int scol = (tid & 1) << 4;
    const int kc0  = (tid & 1) << 1;
    const float* xp = X + (size_t)(m_tile * 128 + srow) * KDIM + scol;
    const float* wp = W + (size_t)(n_tile * 128 + srow) * KDIM + scol;
    const int orow = n_tile * 128 + srow;
    float rp0, rp1, rp2;
    row_coeffs(orow, w, rp0, rp1, rp2);
    const int lane = tid & 63, wv = tid >> 6;
    const int frow = lane & 15, kcl = lane >> 4;
    const int arow0 = (wv >> 1) * 64 + frow;
    const int brow0 = (wv & 1) * 64 + frow;
    auto coef = [&](int t) -> float { return t < 16 ? rp0 : (t < 24 ? rp1 : rp2); };
    auto stage_load = [&](int t, f32x4 a[4], f32x4 b[4]) {
        const f32x4* xq = (const f32x4*)(xp + t * 32);
        const f32x4* wq = (const f32x4*)(wp + t * 32);
#pragma unroll
        for (int j = 0; j < 4; ++j) { a[j] = xq[j]; b[j] = wq[j]; }
    };
    auto stage_write = [&](int buf, const f32x4 a[4], const f32x4 b[4], float cf) {
        u16x8 va[2], vb[2];
#pragma unroll
        for (int j = 0; j < 4; ++j)
#pragma unroll
            for (int e = 0; e < 4; ++e) {
                const int idx = j * 4 + e;
                va[idx >> 3][idx & 7] = f2bf(a[j][e]);
                vb[idx >> 3][idx & 7] = f2bf(b[j][e] * cf);
            }
        *(u16x8*)&Alds[buf][kc0    ][srow][0] = va[0];
        *(u16x8*)&Alds[buf][kc0 + 1][srow][0] = va[1];
        *(u16x8*)&Blds[buf][kc0    ][srow][0] = vb[0];
        *(u16x8*)&Blds[buf][kc0 + 1][srow][0] = vb[1];
    };
    f32x4 acc[4][4];
#pragma unroll
    for (int i = 0; i < 4; ++i)
#pragma unroll
        for (int j = 0; j < 4; ++j) acc[i][j] = (f32x4){0.f, 0.f, 0.f, 0.f};
    {
        f32x4 a[4], b[4];
        stage_load(0, a, b);
        stage_write(0, a, b, coef(0));
    }
    __syncthreads();
    const int NT = KDIM / 32;
    int cur = 0;
    for (int t = 0; t < NT; ++t) {
        f32x4 a[4], b[4];
        if (t + 1 < NT) stage_load(t + 1, a, b);
        s16x8 af[4], bf_[4];
#pragma unroll
        for (int i = 0; i < 4; ++i) {
            af[i]  = *(const s16x8*)&Alds[cur][kcl][arow0 + i * 16][0];
            bf_[i] = *(const s16x8*)&Blds[cur][kcl][brow0 + i * 16][0];
        }
#pragma unroll
        for (int i = 0; i < 4; ++i)
#pragma unroll
            for (int j = 0; j < 4; ++j)
                acc[i][j] = __builtin_amdgcn_mfma_f32_16x16x32_bf16(
                    af[i], bf_[j], acc[i][j], 0, 0, 0);
        if (t + 1 < NT) stage_write(cur ^ 1, a, b, coef(t + 1));
        __syncthreads();
        cur ^= 1;
    }
    const int gm0 = m_tile * 128 + (wv >> 1) * 64 + kcl * 4;
    const int gn0 = n_tile * 128 + (wv & 1) * 64 + frow;
#pragma unroll
    for (int j = 0; j < 4; ++j) {
        const int n = gn0 + j * 16;
        const float bc = bias[n] * row_bias_coef(n, w);
#pragma unroll
        for (int i = 0; i < 4; ++i) {
            float* yp = Y + (size_t)(gm0 + i * 16) * NDIM + n;
            yp[0 * NDIM] = acc[i][j][0] + bc;
            yp[1 * NDIM] = acc[i][j][1] + bc;
            yp[2 * NDIM] = acc[i][j][2] + bc;
            yp[3 * NDIM] = acc[i][j][3] + bc;
        }
    }
}

extern "C" void kernel_launch(void* const* d_in, const int* in_sizes, int n_in,
                              void* d_out, int out_size, void* d_ws, size_t ws_size,
                              hipStream_t stream) {
    const float* X    = (const float*)d_in[0];
    const float* wts  = (const float*)d_in[1];
    const float* W    = (const float*)d_in[2];
    const float* bias = (const float*)d_in[3];
    float* Y = (float*)d_out;

    const int M = in_sizes[0] / KDIM;            // 32768

    const size_t xb_elems = (size_t)M * KDIM;
    const size_t wb_elems = (size_t)NDIM * KDIM;
    const size_t ws_needed = (xb_elems + wb_elems) * sizeof(unsigned short);

    if (ws_size >= ws_needed && (M % 128) == 0) {
        unsigned short* XB = (unsigned short*)d_ws;
        unsigned short* WB = XB + xb_elems;
        prep_x<<<4096, 256, 0, stream>>>(X, XB, (int)(xb_elems / 8));
        prep_w<<<(NDIM * (KDIM / 8)) / 256, 256, 0, stream>>>(W, wts, WB);
        const int nm = M / 128;                  // 256
        const int grid = nm * (NDIM / 128);      // 8192
        mlv2_gemm_v6<<<grid, 256, 0, stream>>>(XB, WB, wts, bias, Y, nm);
    } else {
        const int grid = (M / 128) * (NDIM / 128);
        mlv2_gemm_v1<<<grid, 256, 0, stream>>>(X, wts, W, bias, Y);
    }
}

// Round 7
// 396.023 us; speedup vs baseline: 1.0838x; 1.0838x over previous
//
#include <hip/hip_runtime.h>

#define KDIM 1024
#define NDIM 4096

typedef __attribute__((ext_vector_type(4))) float f32x4;
typedef __attribute__((ext_vector_type(8))) short s16x8;
typedef __attribute__((ext_vector_type(8))) unsigned short u16x8;

__device__ __forceinline__ unsigned short f2bf(float f) {
    union { float f; unsigned u; } v; v.f = f;
    unsigned r = v.u + 0x7FFFu + ((v.u >> 16) & 1u);
    return (unsigned short)(r >> 16);
}

#define GLDS(gsrc, ldst)                                                        \
    __builtin_amdgcn_global_load_lds(                                           \
        (const __attribute__((address_space(1))) unsigned int*)(gsrc),          \
        (__attribute__((address_space(3))) unsigned int*)(ldst), 16, 0, 0)

#define SBAR() __builtin_amdgcn_s_barrier()
#define VMW(n) asm volatile("s_waitcnt vmcnt(" #n ")" ::: "memory")
#define LGKM0() asm volatile("s_waitcnt lgkmcnt(0)" ::: "memory")

__device__ __forceinline__ void row_coeffs(int o, const float* w,
                                           float& rp0, float& rp1, float& rp2) {
    rp2 = (o < 2048 ? w[6] : 0.f) + (o < 3072 ? w[7] : 0.f) + w[8];
    rp1 = rp2 + (o < 1536 ? w[3] : 0.f) + (o < 2304 ? w[4] : 0.f) + (o < 3072 ? w[5] : 0.f);
    rp0 = rp1 + (o < 1024 ? w[0] : 0.f) + (o < 1536 ? w[1] : 0.f) + (o < 2048 ? w[2] : 0.f);
}

__device__ __forceinline__ float row_bias_coef(int n, const float* w) {
    return (n < 1024 ? w[0] : 0.f) + (n < 1536 ? w[1] : 0.f)
         + (n < 2048 ? w[2] : 0.f) + (n < 1536 ? w[3] : 0.f)
         + (n < 2304 ? w[4] : 0.f) + (n < 3072 ? w[5] : 0.f)
         + (n < 2048 ? w[6] : 0.f) + (n < 3072 ? w[7] : 0.f) + w[8];
}

// ---------------- pre-pass: X f32 -> bf16 ----------------
__global__ __launch_bounds__(256) void prep_x(const float* __restrict__ X,
                                              unsigned short* __restrict__ XB, int n8) {
    int i = blockIdx.x * blockDim.x + threadIdx.x;
    const int stride = gridDim.x * blockDim.x;
    for (; i < n8; i += stride) {
        const f32x4* p = (const f32x4*)(X + (size_t)i * 8);
        f32x4 a = p[0], b = p[1];
        u16x8 o;
        o[0] = f2bf(a[0]); o[1] = f2bf(a[1]); o[2] = f2bf(a[2]); o[3] = f2bf(a[3]);
        o[4] = f2bf(b[0]); o[5] = f2bf(b[1]); o[6] = f2bf(b[2]); o[7] = f2bf(b[3]);
        *(u16x8*)(XB + (size_t)i * 8) = o;
    }
}

// ---------------- pre-pass: W_mix = W * coeff -> bf16 ----------------
__global__ __launch_bounds__(256) void prep_w(const float* __restrict__ W,
                                              const float* __restrict__ wts,
                                              unsigned short* __restrict__ WB) {
    const int g = blockIdx.x * blockDim.x + threadIdx.x;
    if (g >= NDIM * (KDIM / 8)) return;
    const int o = g >> 7, ig = g & 127;
    float w[9];
#pragma unroll
    for (int k = 0; k < 9; ++k) w[k] = wts[k];
    float rp0, rp1, rp2;
    row_coeffs(o, w, rp0, rp1, rp2);
    const float cf = ig < 64 ? rp0 : (ig < 96 ? rp1 : rp2);
    const f32x4* p = (const f32x4*)(W + (size_t)g * 8);
    f32x4 a = p[0], b = p[1];
    u16x8 ov;
    ov[0] = f2bf(a[0] * cf); ov[1] = f2bf(a[1] * cf); ov[2] = f2bf(a[2] * cf); ov[3] = f2bf(a[3] * cf);
    ov[4] = f2bf(b[0] * cf); ov[5] = f2bf(b[1] * cf); ov[6] = f2bf(b[2] * cf); ov[7] = f2bf(b[3] * cf);
    *(u16x8*)(WB + (size_t)g * 8) = ov;
}

// ---------------- main GEMM v7: 256x256, BK=32, ring-4 LDS, L2-pinned mapping ----------------
// vs v5 (768 TF, MfmaUtil 30%): two changes targeting the ~1800cyc/K-tile staging stall:
// (1) per-XCD n-pinning: each XCD serves only 2 n-tiles -> WB working set 1MB,
//     L2-resident whole kernel; block pairs (2j,2j+1) share m_tile -> A-panel
//     read by 2 concurrent CUs (2nd read L2-hits). Staging latency ~900 -> ~250cyc.
// (2) ring-4 LDS (128 KiB), vmcnt(8): 3 K-tiles prefetched, 12 loads/wave in
//     flight, >=2 iterations of slack per load.
__global__ __launch_bounds__(512, 2) void mlv2_gemm_v7(
    const unsigned short* __restrict__ XB,
    const unsigned short* __restrict__ WB,
    const float* __restrict__ wts,
    const float* __restrict__ bias,
    float* __restrict__ Y)
{
    __shared__ unsigned short LDS[4 * 16384];   // 128 KiB: 4 bufs x (A 16KB + B 16KB)

    const int tid = (int)threadIdx.x;
    const int l   = tid & 63;
    const int w   = tid >> 6;      // wave 0..7
    const int wm  = w >> 2;        // 0..1
    const int wn  = w & 3;         // 0..3

    const int bid = (int)blockIdx.x;
    const int xcd = bid & 7;                 // HW round-robins blocks over XCDs
    const int i   = bid >> 3;                // 0..255 within XCD
    const int n_tile = xcd * 2 + (i & 1);    // XCD pinned to 2 n-tiles (WB slice 1MB, L2-resident)
    const int m_tile = i >> 1;               // consecutive pair shares m_tile (A L2-hit)
    const int m0 = m_tile * 256;
    const int n0 = n_tile * 256;

    // ---- frag-read lane constants (chunk-XOR swizzle -> lane constant; 0 conflicts measured)
    const int rl = l & 15;
    const unsigned cw = (unsigned)((((l >> 4) ^ ((l >> 1) & 3)) * 8));
    unsigned offA[8], offB[4];
#pragma unroll
    for (int m = 0; m < 8; ++m)
        offA[m] = (unsigned)((wm * 128 + m * 16 + rl) * 32) + cw;
#pragma unroll
    for (int n = 0; n < 4; ++n)
        offB[n] = 8192u + (unsigned)((wn * 64 + n * 16 + rl) * 32) + cw;

    // ---- staging: wave w stages rows [32w,32w+32) of A and B; linear LDS dest,
    // inverse-swizzled per-lane global source (chunk c of row r at c ^ ((r>>1)&3)).
    const int cg = (((l & 3) ^ ((l >> 3) & 3)) * 8);
    const int r0 = w * 32 + (l >> 2);
    const unsigned short* sA0 = XB + (size_t)(m0 + r0) * KDIM + cg;
    const unsigned short* sA1 = XB + (size_t)(m0 + r0 + 16) * KDIM + cg;
    const unsigned short* sB0 = WB + (size_t)(n0 + r0) * KDIM + cg;
    const unsigned short* sB1 = WB + (size_t)(n0 + r0 + 16) * KDIM + cg;
    const unsigned dA0 = (unsigned)(w * 1024);
    const unsigned dA1 = dA0 + 512;
    const unsigned dB0 = 8192u + dA0;
    const unsigned dB1 = 8192u + dA1;

    auto stage = [&](int buf, int kt) {
        const int ko = kt * 32;
        const unsigned ob = (unsigned)buf * 16384u;
        GLDS(sA0 + ko, &LDS[ob + dA0]);
        GLDS(sA1 + ko, &LDS[ob + dA1]);
        GLDS(sB0 + ko, &LDS[ob + dB0]);
        GLDS(sB1 + ko, &LDS[ob + dB1]);
    };

    f32x4 acc[8][4];
#pragma unroll
    for (int m = 0; m < 8; ++m)
#pragma unroll
        for (int n = 0; n < 4; ++n) acc[m][n] = (f32x4){0.f, 0.f, 0.f, 0.f};

    auto compute = [&](int buf) {
        const unsigned short* base = &LDS[(unsigned)buf * 16384u];
        s16x8 af[8], bfr[4];
#pragma unroll
        for (int n = 0; n < 4; ++n) bfr[n] = *(const s16x8*)(base + offB[n]);
#pragma unroll
        for (int m = 0; m < 8; ++m) af[m] = *(const s16x8*)(base + offA[m]);
        __builtin_amdgcn_s_setprio(1);
#pragma unroll
        for (int m = 0; m < 8; ++m)
#pragma unroll
            for (int n = 0; n < 4; ++n)
                acc[m][n] = __builtin_amdgcn_mfma_f32_16x16x32_bf16(
                    af[m], bfr[n], acc[m][n], 0, 0, 0);
        __builtin_amdgcn_s_setprio(0);
    };

    // prologue: stage kt 0,1,2 (12 loads); wait kt0 (8 stay in flight)
    stage(0, 0); stage(1, 1); stage(2, 2);
    VMW(8);
    SBAR();

    // steady: iter kt reads buf[kt&3]; stages kt+3 into buf[(kt+3)&3] (= buf read
    // at iter kt-1 -- its reads retired before kt-1's end barrier via LGKM0).
    // VMW(8): kt+2,kt+3 in flight (8), kt+1 guaranteed landed.
    for (int kt = 0; kt < 29; ++kt) {
        stage((kt + 3) & 3, kt + 3);
        compute(kt & 3);
        VMW(8); LGKM0(); SBAR();
    }
    // kt=29: outstanding = {30,31}; need 30 -> VMW(4)
    compute(29 & 3);
    VMW(4); LGKM0(); SBAR();
    // kt=30: need 31 -> VMW(0)
    compute(30 & 3);
    VMW(0); LGKM0(); SBAR();
    // kt=31
    compute(31 & 3);

    // ---- epilogue: + bias[n] * rowcoef(n)
    float w9[9];
#pragma unroll
    for (int k = 0; k < 9; ++k) w9[k] = wts[k];
    const int gmb = m0 + wm * 128 + (l >> 4) * 4;
    const int gnb = n0 + wn * 64 + rl;
#pragma unroll
    for (int n = 0; n < 4; ++n) {
        const int gn = gnb + n * 16;
        const float bc = bias[gn] * row_bias_coef(gn, w9);
#pragma unroll
        for (int m = 0; m < 8; ++m) {
            float* yp = Y + (size_t)(gmb + m * 16) * NDIM + gn;
            yp[0 * NDIM] = acc[m][n][0] + bc;
            yp[1 * NDIM] = acc[m][n][1] + bc;
            yp[2 * NDIM] = acc[m][n][2] + bc;
            yp[3 * NDIM] = acc[m][n][3] + bc;
        }
    }
}

// ---------------- fallback (round-1 fused kernel, validated) ----------------
__global__ __launch_bounds__(256, 2) void mlv2_gemm_v1(
    const float* __restrict__ X, const float* __restrict__ wts,
    const float* __restrict__ W, const float* __restrict__ bias,
    float* __restrict__ Y)
{
    __shared__ unsigned short Alds[2][4][128][8];
    __shared__ unsigned short Blds[2][4][128][8];
    const int tid = (int)threadIdx.x;
    const int bid = (int)blockIdx.x;
    const int wg  = (bid & 7) * 1024 + (bid >> 3);
    const int n_tile = wg & 31;
    const int m_tile = wg >> 5;
    float w[9];
#pragma unroll
    for (int k = 0; k < 9; ++k) w[k] = wts[k];
    const int srow = tid >> 1;
    const int scol = (tid & 1) << 4;
    const int kc0  = (tid & 1) << 1;
    const float* xp = X + (size_t)(m_tile * 128 + srow) * KDIM + scol;
    const float* wp = W + (size_t)(n_tile * 128 + srow) * KDIM + scol;
    const int orow = n_tile * 128 + srow;
    float rp0, rp1, rp2;
    row_coeffs(orow, w, rp0, rp1, rp2);
    const int lane = tid & 63, wv = tid >> 6;
    const int frow = lane & 15, kcl = lane >> 4;
    const int arow0 = (wv >> 1) * 64 + frow;
    const int brow0 = (wv & 1) * 64 + frow;
    auto coef = [&](int t) -> float { return t < 16 ? rp0 : (t < 24 ? rp1 : rp2); };
    auto stage_load = [&](int t, f32x4 a[4], f32x4 b[4]) {
        const f32x4* xq = (const f32x4*)(xp + t * 32);
        const f32x4* wq = (const f32x4*)(wp + t * 32);
#pragma unroll
        for (int j = 0; j < 4; ++j) { a[j] = xq[j]; b[j] = wq[j]; }
    };
    auto stage_write = [&](int buf, const f32x4 a[4], const f32x4 b[4], float cf) {
        u16x8 va[2], vb[2];
#pragma unroll
        for (int j = 0; j < 4; ++j)
#pragma unroll
            for (int e = 0; e < 4; ++e) {
                const int idx = j * 4 + e;
                va[idx >> 3][idx & 7] = f2bf(a[j][e]);
                vb[idx >> 3][idx & 7] = f2bf(b[j][e] * cf);
            }
        *(u16x8*)&Alds[buf][kc0    ][srow][0] = va[0];
        *(u16x8*)&Alds[buf][kc0 + 1][srow][0] = va[1];
        *(u16x8*)&Blds[buf][kc0    ][srow][0] = vb[0];
        *(u16x8*)&Blds[buf][kc0 + 1][srow][0] = vb[1];
    };
    f32x4 acc[4][4];
#pragma unroll
    for (int i = 0; i < 4; ++i)
#pragma unroll
        for (int j = 0; j < 4; ++j) acc[i][j] = (f32x4){0.f, 0.f, 0.f, 0.f};
    {
        f32x4 a[4], b[4];
        stage_load(0, a, b);
        stage_write(0, a, b, coef(0));
    }
    __syncthreads();
    const int NT = KDIM / 32;
    int cur = 0;
    for (int t = 0; t < NT; ++t) {
        f32x4 a[4], b[4];
        if (t + 1 < NT) stage_load(t + 1, a, b);
        s16x8 af[4], bf_[4];
#pragma unroll
        for (int i = 0; i < 4; ++i) {
            af[i]  = *(const s16x8*)&Alds[cur][kcl][arow0 + i * 16][0];
            bf_[i] = *(const s16x8*)&Blds[cur][kcl][brow0 + i * 16][0];
        }
#pragma unroll
        for (int i = 0; i < 4; ++i)
#pragma unroll
            for (int j = 0; j < 4; ++j)
                acc[i][j] = __builtin_amdgcn_mfma_f32_16x16x32_bf16(
                    af[i], bf_[j], acc[i][j], 0, 0, 0);
        if (t + 1 < NT) stage_write(cur ^ 1, a, b, coef(t + 1));
        __syncthreads();
        cur ^= 1;
    }
    const int gm0 = m_tile * 128 + (wv >> 1) * 64 + kcl * 4;
    const int gn0 = n_tile * 128 + (wv & 1) * 64 + frow;
#pragma unroll
    for (int j = 0; j < 4; ++j) {
        const int n = gn0 + j * 16;
        const float bc = bias[n] * row_bias_coef(n, w);
#pragma unroll
        for (int i = 0; i < 4; ++i) {
            float* yp = Y + (size_t)(gm0 + i * 16) * NDIM + n;
            yp[0 * NDIM] = acc[i][j][0] + bc;
            yp[1 * NDIM] = acc[i][j][1] + bc;
            yp[2 * NDIM] = acc[i][j][2] + bc;
            yp[3 * NDIM] = acc[i][j][3] + bc;
        }
    }
}

extern "C" void kernel_launch(void* const* d_in, const int* in_sizes, int n_in,
                              void* d_out, int out_size, void* d_ws, size_t ws_size,
                              hipStream_t stream) {
    const float* X    = (const float*)d_in[0];
    const float* wts  = (const float*)d_in[1];
    const float* W    = (const float*)d_in[2];
    const float* bias = (const float*)d_in[3];
    float* Y = (float*)d_out;

    const int M = in_sizes[0] / KDIM;            // 32768

    const size_t xb_elems = (size_t)M * KDIM;
    const size_t wb_elems = (size_t)NDIM * KDIM;
    const size_t ws_needed = (xb_elems + wb_elems) * sizeof(unsigned short);

    if (ws_size >= ws_needed && (M % 256) == 0) {
        unsigned short* XB = (unsigned short*)d_ws;
        unsigned short* WB = XB + xb_elems;
        prep_x<<<4096, 256, 0, stream>>>(X, XB, (int)(xb_elems / 8));
        prep_w<<<(NDIM * (KDIM / 8)) / 256, 256, 0, stream>>>(W, wts, WB);
        const int grid = (M / 256) * (NDIM / 256);   // 2048
        mlv2_gemm_v7<<<grid, 512, 0, stream>>>(XB, WB, wts, bias, Y);
    } else {
        const int grid = (M / 128) * (NDIM / 128);
        mlv2_gemm_v1<<<grid, 256, 0, stream>>>(X, wts, W, bias, Y);
    }
}